// Round 10
// baseline (175.315 us; speedup 1.0000x reference)
//
#include <hip/hip_runtime.h>
#include <hip/hip_bf16.h>

#define HH 512
#define WW 640
#define HW (HH*WW)
#define NT 256
#define IMPLANEP (432*8 + 8)    // img plane stride in shorts (36x12 pix, +16B pad)
#define H1PLANEP (360*8 + 8)    // h1 plane stride in shorts (36x10 pix, +16B pad)

typedef short short8  __attribute__((ext_vector_type(8)));
typedef short short4v __attribute__((ext_vector_type(4)));
typedef float f32x16  __attribute__((ext_vector_type(16)));
typedef float f32x4   __attribute__((ext_vector_type(4)));

__device__ inline short f2bf(float f) {
    __hip_bfloat16 h = __float2bfloat16(f);
    short s; __builtin_memcpy(&s, &h, 2);
    return s;
}

// ---- prep: fold BN into w1, bias as 10th tap row, transpose to MFMA layouts ----
__global__ void prep_weights(const float* __restrict__ w1, const float* __restrict__ b1,
                             const float* __restrict__ gamma, const float* __restrict__ beta,
                             const float* __restrict__ rmean, const float* __restrict__ rvar,
                             const float* __restrict__ w2,
                             short* __restrict__ ws_w1, short* __restrict__ ws_w2)
{
    int tid = blockIdx.x*blockDim.x + threadIdx.x;
    int stride = gridDim.x*blockDim.x;
    for (int i = tid; i < 4608; i += stride) {          // w1: [oc][c][t] -> [t][oc32][c16] * A_oc
        int oc = i / 144, rem = i - oc*144, c = rem / 9, t = rem - c*9;
        float a = gamma[oc] * rsqrtf(rvar[oc] + 1e-5f);
        ws_w1[t*512 + oc*16 + c] = f2bf(w1[i] * a);
    }
    for (int i = tid; i < 512; i += stride) {           // tap 9 = bias row (c==0 one-hot)
        int oc = i >> 4, c = i & 15;
        float a = gamma[oc] * rsqrtf(rvar[oc] + 1e-5f);
        float bias = beta[oc] + (b1[oc] - rmean[oc]) * a;
        ws_w1[9*512 + i] = (c == 0) ? f2bf(bias) : (short)0;
    }
    for (int i = tid; i < 4608; i += stride) {          // w2: [f][c][t] -> [t][f16][c32], f>=9 zero
        int t = i >> 9, f = (i >> 5) & 15, c = i & 31;
        float val = (f < 9) ? w2[(f*32 + c)*9 + t] : 0.f;
        ws_w2[i] = f2bf(val);
    }
}

// -------- persistent fused kernel: 1024 blocks x 5 tiles, reg-prefetch pipeline --------
__launch_bounds__(NT, 4)
__global__ void fastprop_main(const float* __restrict__ depth,
                              const float* __restrict__ img,
                              const short* __restrict__ ws_w1,
                              const short* __restrict__ ws_w2,
                              float* __restrict__ out)
{
    __shared__ short s_img[2*IMPLANEP];   // [ch-plane][pix 36x12][8ch] bf16 (13856 B)
    __shared__ short s_h1 [4*H1PLANEP];   // [ch-plane][pix 36x10][8ch] bf16 (23104 B)
    __shared__ float s_depth[340];        // 34x10 replicate-clamped fp32    (1360 B)

    const int tid  = threadIdx.x;
    const int lane = tid & 63;
    const int wid  = tid >> 6;

    // block -> 5 consecutive tiles on one XCD (halo columns overlap tile-to-tile)
    const int nid      = blockIdx.x;              // 1024 blocks = 8 XCDs x 128
    const int base_oid = (nid & 7)*640 + (nid >> 3)*5;

    // static per-thread granule geometry (img tile 36x12, 2 granules/pixel)
    int PIX[4], HALF[4], IY[4], IX[4]; bool ACT[4];
    #pragma unroll
    for (int j = 0; j < 4; ++j) {
        int g = tid + j*NT;
        ACT[j]  = (g < 864);
        int pixel = g >> 1;
        PIX[j]  = pixel; HALF[j] = g & 1;
        IY[j]   = pixel / 36; IX[j] = pixel - 36*(pixel/36);
    }

    float r[4][8]; float msk[4]; float d0 = 0.f, d1 = 0.f;

    auto load_tile = [&](int oid) {
        int bz = oid / 1280; int rm = oid - bz*1280;
        int by = rm / 20;    int bx = rm - by*20;
        int gy0 = by*8, gx0 = bx*32;
        const float* imgb = img   + (size_t)bz*16*HW;
        const float* dpb  = depth + (size_t)bz*HW;
        #pragma unroll
        for (int j = 0; j < 4; ++j) {
            if (ACT[j]) {
                int gy = gy0 + IY[j] - 2, gx = gx0 + IX[j] - 2;
                bool v = ((unsigned)gy < HH) && ((unsigned)gx < WW);
                int cy = min(max(gy, 0), HH-1), cx = min(max(gx, 0), WW-1);
                const float* p = imgb + (size_t)(HALF[j]*8)*HW + cy*WW + cx;
                msk[j] = v ? 1.f : 0.f;
                #pragma unroll
                for (int c = 0; c < 8; ++c) r[j][c] = p[c*HW];
            }
        }
        {
            int ty = tid / 34, tx = tid - ty*34;
            int gy = min(max(gy0 + ty - 1, 0), HH-1);
            int gx = min(max(gx0 + tx - 1, 0), WW-1);
            d0 = dpb[gy*WW + gx];
        }
        if (tid < 84) {
            int i1 = tid + 256;
            int ty = i1 / 34, tx = i1 - ty*34;
            int gy = min(max(gy0 + ty - 1, 0), HH-1);
            int gx = min(max(gx0 + tx - 1, 0), WW-1);
            d1 = dpb[gy*WW + gx];
        }
    };

    load_tile(base_oid);                          // prologue prefetch

    for (int t = 0; t < 5; ++t) {
        const int oid = base_oid + t;
        int bz = oid / 1280; int rm = oid - bz*1280;
        int by = rm / 20;    int bx = rm - by*20;
        const int gy0 = by*8, gx0 = bx*32;

        __syncthreads();     // prev iter done reading s_img/s_depth/s_h1

        // ---- dump prefetched regs -> LDS ----
        #pragma unroll
        for (int j = 0; j < 4; ++j) {
            if (ACT[j]) {
                short8 vv;
                #pragma unroll
                for (int c = 0; c < 8; ++c) vv[c] = f2bf(msk[j] * r[j][c]);
                *(short8*)&s_img[HALF[j]*IMPLANEP + PIX[j]*8] = vv;
            }
        }
        s_depth[tid] = d0;
        if (tid < 84) s_depth[tid + 256] = d1;

        // ---- issue next tile's global loads (latency hides under conv1+conv2) ----
        if (t < 4) load_tile(oid + 1);

        __syncthreads();     // staging visible

        // ---- conv1 (32x32x16 MFMA, 9 taps + bias tap) -> s_h1 channel-planes ----
        {
            const int oc = lane & 31, cg = lane >> 5;
            short8 a1[10];
            #pragma unroll
            for (int tt = 0; tt < 10; ++tt)
                a1[tt] = *(const short8*)&ws_w1[tt*512 + oc*16 + cg*8];
            short8 bb = (short8)0;               // bias-tap B: one-hot 1.0 at k==0
            bb[0] = (cg == 0) ? (short)0x3F80 : (short)0;

            const int OFS1[9] = {0, 8, 16, 288, 296, 304, 576, 584, 592};
            const int px = lane & 31;

            #pragma unroll
            for (int gi = 0; gi < 3; ++gi) {
                int g    = wid + gi*4;
                int hp   = g*32 + px;
                int base = cg*IMPLANEP + hp*8;
                f32x16 acc;
                #pragma unroll
                for (int i = 0; i < 16; ++i) acc[i] = 0.f;
                acc = __builtin_amdgcn_mfma_f32_32x32x16_bf16(a1[9], bb, acc, 0, 0, 0);
                #pragma unroll
                for (int tt = 0; tt < 9; ++tt)
                    acc = __builtin_amdgcn_mfma_f32_32x32x16_bf16(
                             a1[tt], *(const short8*)&s_img[base + OFS1[tt]], acc, 0, 0, 0);

                if (hp < 360) {
                    unsigned hy = (unsigned)hp / 36u;
                    int hx = hp - (int)hy*36;
                    int gy = gy0 + (int)hy - 1, gx = gx0 + hx - 1;
                    bool inb = ((unsigned)gy < HH) && ((unsigned)gx < WW);
                    #pragma unroll
                    for (int q = 0; q < 4; ++q) {      // plane q = channels 8q..8q+7
                        short4v h;
                        #pragma unroll
                        for (int j = 0; j < 4; ++j) {
                            float hv = fmaxf(acc[q*4 + j], 0.f);
                            h[j] = inb ? f2bf(hv) : (short)0;
                        }
                        *(short4v*)&s_h1[q*H1PLANEP + hp*8 + 4*cg] = h;
                    }
                }
            }
        }
        __syncthreads();     // h1 visible

        // ---- conv2 (16x16x32 MFMA) sliding row-pair + softmax + gather ----
        {
            const int fl = lane & 15, cg2 = lane >> 4;
            short8 a2[9];
            #pragma unroll
            for (int tt = 0; tt < 9; ++tt)
                a2[tt] = *(const short8*)&ws_w2[tt*512 + fl*32 + cg2*8];

            const int r0 = 2*wid;                // this wave's output rows r0, r0+1

            #pragma unroll
            for (int chh = 0; chh < 2; ++chh) {  // column halves 0-15, 16-31
                const int ox0 = chh*16;
                const int colbase = cg2*H1PLANEP + (ox0 + fl)*8;

                short8 F[4][3];                  // h1 rows r0..r0+3, dx 0..2
                #pragma unroll
                for (int i = 0; i < 4; ++i)
                    #pragma unroll
                    for (int dx = 0; dx < 3; ++dx)
                        F[i][dx] = *(const short8*)&s_h1[colbase + ((r0 + i)*36 + dx)*8];

                f32x4 acc0, acc1;
                #pragma unroll
                for (int i = 0; i < 4; ++i) { acc0[i] = 0.f; acc1[i] = 0.f; }
                #pragma unroll
                for (int i = 0; i < 3; ++i)
                    #pragma unroll
                    for (int dx = 0; dx < 3; ++dx)
                        acc0 = __builtin_amdgcn_mfma_f32_16x16x32_bf16(
                                 a2[i*3 + dx], F[i][dx], acc0, 0, 0, 0);
                #pragma unroll
                for (int i = 0; i < 3; ++i)
                    #pragma unroll
                    for (int dx = 0; dx < 3; ++dx)
                        acc1 = __builtin_amdgcn_mfma_f32_16x16x32_bf16(
                                 a2[i*3 + dx], F[i + 1][dx], acc1, 0, 0, 0);

                #pragma unroll
                for (int rr = 0; rr < 2; ++rr) {
                    f32x4 lg = rr ? acc1 : acc0;
                    int oy = r0 + rr, ox = ox0 + fl;
                    float num = 0.f, den = 0.f;
                    #pragma unroll
                    for (int q = 0; q < 4; ++q) {
                        int f = cg2*4 + q;           // conv2 output channel
                        if (f < 9) {
                            float e = __expf(lg[q]);
                            int fy = f/3, fx = f - fy*3;
                            float d = s_depth[(oy + fy)*34 + (ox + fx)];
                            den += e; num += e * d;
                        }
                    }
                    num += __shfl_xor(num, 16); den += __shfl_xor(den, 16);
                    num += __shfl_xor(num, 32); den += __shfl_xor(den, 32);
                    if (cg2 == 0)
                        out[(size_t)bz*HW + (size_t)(gy0 + oy)*WW + (gx0 + ox)] = num / den;
                }
            }
        }
    }
}

extern "C" void kernel_launch(void* const* d_in, const int* in_sizes, int n_in,
                              void* d_out, int out_size, void* d_ws, size_t ws_size,
                              hipStream_t stream) {
    const float* depth = (const float*)d_in[0];
    const float* img   = (const float*)d_in[1];
    const float* w1    = (const float*)d_in[2];
    const float* b1    = (const float*)d_in[3];
    const float* gamma = (const float*)d_in[4];
    const float* beta  = (const float*)d_in[5];
    const float* rmean = (const float*)d_in[6];
    const float* rvar  = (const float*)d_in[7];
    const float* w2    = (const float*)d_in[8];
    float* out = (float*)d_out;

    short* ws_w1 = (short*)d_ws;          // 5120 shorts (10 taps x 512)
    short* ws_w2 = ws_w1 + 5120;          // 4608 shorts

    prep_weights<<<16, 256, 0, stream>>>(w1, b1, gamma, beta, rmean, rvar, w2,
                                         ws_w1, ws_w2);
    fastprop_main<<<1024, NT, 0, stream>>>(depth, img, ws_w1, ws_w2, out);
}

// Round 11
// 82.548 us; speedup vs baseline: 2.1238x; 2.1238x over previous
//
#include <hip/hip_runtime.h>
#include <hip/hip_bf16.h>

#define HH 512
#define WW 640
#define HW (HH*WW)
#define PWI 644                 // img pad 2 each side
#define PHI 516
#define PWD 642                 // depth pad 1 each side
#define PHD 514
#define NIP (4*PHI*PWI)         // 1,329,216 padded img pixels
#define NDP (4*PHD*PWD)         // 1,319,952 padded depth pixels
#define IMPLANE 3456            // shorts per img LDS plane (432 granules * 8)
#define H1PLANE 2880            // shorts per h1 LDS plane (360 px * 8)

typedef short short8  __attribute__((ext_vector_type(8)));
typedef short short4v __attribute__((ext_vector_type(4)));
typedef float f32x16  __attribute__((ext_vector_type(16)));
typedef float f32x4   __attribute__((ext_vector_type(4)));

__device__ inline short f2bf(float f) {
    __hip_bfloat16 h = __float2bfloat16(f);
    short s; __builtin_memcpy(&s, &h, 2);
    return s;
}

// ---- prep: fold BN into w1, bias as 10th tap row, transpose to MFMA layouts ----
__global__ void prep_weights(const float* __restrict__ w1, const float* __restrict__ b1,
                             const float* __restrict__ gamma, const float* __restrict__ beta,
                             const float* __restrict__ rmean, const float* __restrict__ rvar,
                             const float* __restrict__ w2,
                             short* __restrict__ ws_w1, short* __restrict__ ws_w2)
{
    int tid = blockIdx.x*blockDim.x + threadIdx.x;
    int stride = gridDim.x*blockDim.x;
    for (int i = tid; i < 4608; i += stride) {          // w1: [oc][c][t] -> [t][oc32][c16] * A_oc
        int oc = i / 144, rem = i - oc*144, c = rem / 9, t = rem - c*9;
        float a = gamma[oc] * rsqrtf(rvar[oc] + 1e-5f);
        ws_w1[t*512 + oc*16 + c] = f2bf(w1[i] * a);
    }
    for (int i = tid; i < 512; i += stride) {           // tap 9 = bias row (c==0 one-hot)
        int oc = i >> 4, c = i & 15;
        float a = gamma[oc] * rsqrtf(rvar[oc] + 1e-5f);
        float bias = beta[oc] + (b1[oc] - rmean[oc]) * a;
        ws_w1[9*512 + i] = (c == 0) ? f2bf(bias) : (short)0;
    }
    for (int i = tid; i < 4608; i += stride) {          // w2: [f][c][t] -> [t][f16][c32], f>=9 zero
        int t = i >> 9, f = (i >> 5) & 15, c = i & 31;
        float val = (f < 9) ? w2[(f*32 + c)*9 + t] : 0.f;
        ws_w2[i] = f2bf(val);
    }
}

// ---- prep_pad: img -> zero-padded NHWC bf16; depth -> replicate-padded fp32 ----
__global__ void prep_pad(const float* __restrict__ depth, const float* __restrict__ img,
                         short* __restrict__ img_pad, float* __restrict__ depth_pad)
{
    int idx = blockIdx.x*256 + threadIdx.x;
    if (idx < NIP) {
        int b = idx / (PHI*PWI); int rem = idx - b*(PHI*PWI);
        int py = rem / PWI, px = rem - py*PWI;
        short8 v0 = (short8)0, v1 = (short8)0;
        if (py >= 2 && py < PHI-2 && px >= 2 && px < PWI-2) {
            const float* p = img + (size_t)b*16*HW + (py-2)*WW + (px-2);
            #pragma unroll
            for (int c = 0; c < 8; ++c) v0[c] = f2bf(p[c*HW]);
            #pragma unroll
            for (int c = 0; c < 8; ++c) v1[c] = f2bf(p[(c+8)*HW]);
        }
        *(short8*)&img_pad[(size_t)idx*16]     = v0;
        *(short8*)&img_pad[(size_t)idx*16 + 8] = v1;
    }
    if (idx < NDP) {
        int b = idx / (PHD*PWD); int rem = idx - b*(PHD*PWD);
        int py = rem / PWD, px = rem - py*PWD;
        int cy = min(max(py - 1, 0), HH-1), cx = min(max(px - 1, 0), WW-1);
        depth_pad[idx] = depth[(size_t)b*HW + cy*WW + cx];
    }
}

// ---- main: persistent 2-tile blocks, global_load_lds DMA double-buffer ----
__launch_bounds__(256, 4)
__global__ void fastprop_main(const short* __restrict__ img_pad,
                              const float* __restrict__ depth_pad,
                              const short* __restrict__ ws_w1,
                              const short* __restrict__ ws_w2,
                              float* __restrict__ out)
{
    __shared__ short s_img[2][6912];    // [buf][plane-major 864 granules x 8 shorts]
    __shared__ short s_h1[11520];       // [plane 4][360 px][8ch]
    __shared__ float s_depth[2][340];   // [buf][34x10]

    const int tid = threadIdx.x, lane = tid & 63, wid = tid >> 6;

    // 2560 blocks = 8 XCDs x 320; each owns tiles oid0, oid0+1 (bx-adjacent)
    const int nid  = blockIdx.x;
    const int oid0 = (nid & 7)*640 + (nid >> 3)*2;

    // ---- DMA lane-offset precompute (tile-invariant) ----
    int SIMG[4]; bool MIMG[4];
    #pragma unroll
    for (int i = 0; i < 4; ++i) {
        int k = wid + 4*i, g = k*64 + lane;
        MIMG[i] = (k < 14) && (g < 864);
        int pl  = (g >= 432) ? 1 : 0;
        int pix = g - 432*pl;
        int iy = pix / 36, ix = pix - 36*iy;
        SIMG[i] = (iy*PWI + ix)*2 + pl;          // granule units
    }
    int SDEP[2]; bool MDEP[2];
    #pragma unroll
    for (int i = 0; i < 2; ++i) {
        int k = wid + 4*i, g = k*64 + lane;
        MDEP[i] = (k < 6) && (g < 340);
        int ty = g / 34, tx = g - 34*ty;
        SDEP[i] = ty*PWD + tx;                   // dword units
    }

    auto dma = [&](int buf, int oid) {
        int bz = oid / 1280; int rm = oid - bz*1280;
        int by = rm / 20,  bx = rm - 20*by;
        int gy0 = by*8, gx0 = bx*32;
        int tbi = ((bz*PHI + gy0)*PWI + gx0)*2;  // granule units
        int tbd = (bz*PHD + gy0)*PWD + gx0;
        #pragma unroll
        for (int i = 0; i < 4; ++i) {
            int k = wid + 4*i;
            if (MIMG[i])
                __builtin_amdgcn_global_load_lds(
                    (const void*)(img_pad + (size_t)(tbi + SIMG[i])*8),
                    (void*)&s_img[buf][k*512], 16, 0, 0);
        }
        #pragma unroll
        for (int i = 0; i < 2; ++i) {
            int k = wid + 4*i;
            if (MDEP[i])
                __builtin_amdgcn_global_load_lds(
                    (const void*)(depth_pad + (size_t)(tbd + SDEP[i])),
                    (void*)&s_depth[buf][k*64], 4, 0, 0);
        }
    };

    dma(0, oid0);

    #pragma unroll
    for (int t = 0; t < 2; ++t) {
        const int oid = oid0 + t;
        int bz = oid / 1280; int rm = oid - bz*1280;
        int by = rm / 20,  bx = rm - 20*by;
        const int gy0 = by*8, gx0 = bx*32;

        __syncthreads();   // compiler drains vmcnt here -> buf[t] DMA complete; s_h1 free

        // ---- conv1 (32x32x16 MFMA, 9 taps + bias tap) -> s_h1 ----
        {
            const int oc = lane & 31, cg = lane >> 5;
            short8 a1[10];
            #pragma unroll
            for (int tt = 0; tt < 10; ++tt)
                a1[tt] = *(const short8*)&ws_w1[tt*512 + oc*16 + cg*8];
            short8 bb = (short8)0;               // bias-tap B: one-hot 1.0 at k==0
            bb[0] = (cg == 0) ? (short)0x3F80 : (short)0;

            const int OFS1[9] = {0, 8, 16, 288, 296, 304, 576, 584, 592};
            const int px = lane & 31;

            #pragma unroll
            for (int gi = 0; gi < 3; ++gi) {
                int g    = wid + gi*4;
                int hp   = g*32 + px;
                int base = cg*IMPLANE + hp*8;
                f32x16 acc;
                #pragma unroll
                for (int i = 0; i < 16; ++i) acc[i] = 0.f;
                acc = __builtin_amdgcn_mfma_f32_32x32x16_bf16(a1[9], bb, acc, 0, 0, 0);
                #pragma unroll
                for (int tt = 0; tt < 9; ++tt)
                    acc = __builtin_amdgcn_mfma_f32_32x32x16_bf16(
                             a1[tt], *(const short8*)&s_img[t][base + OFS1[tt]], acc, 0, 0, 0);

                if (hp < 360) {
                    unsigned hy = (unsigned)hp / 36u;
                    int hx = hp - (int)hy*36;
                    int gy = gy0 + (int)hy - 1, gx = gx0 + hx - 1;
                    bool inb = ((unsigned)gy < HH) && ((unsigned)gx < WW);
                    #pragma unroll
                    for (int q = 0; q < 4; ++q) {      // plane q = channels 8q..8q+7
                        short4v h;
                        #pragma unroll
                        for (int j = 0; j < 4; ++j) {
                            float hv = fmaxf(acc[q*4 + j], 0.f);
                            h[j] = inb ? f2bf(hv) : (short)0;
                        }
                        *(short4v*)&s_h1[q*H1PLANE + hp*8 + 4*cg] = h;
                    }
                }
            }
        }
        __syncthreads();   // h1 visible (no vmem outstanding -> cheap drain)

        if (t == 0) dma(1, oid0 + 1);   // tile1 DMA hides under conv2(t=0)

        // ---- conv2 (16x16x32 MFMA) sliding row-pair + softmax + gather ----
        {
            const int fl = lane & 15, cg2 = lane >> 4;
            short8 a2[9];
            #pragma unroll
            for (int tt = 0; tt < 9; ++tt)
                a2[tt] = *(const short8*)&ws_w2[tt*512 + fl*32 + cg2*8];

            const int r0 = 2*wid;                // this wave's output rows r0, r0+1

            #pragma unroll
            for (int chh = 0; chh < 2; ++chh) {  // column halves 0-15, 16-31
                const int ox0 = chh*16;
                const int colbase = cg2*H1PLANE + (ox0 + fl)*8;

                short8 F[4][3];                  // h1 rows r0..r0+3, dx 0..2
                #pragma unroll
                for (int i = 0; i < 4; ++i)
                    #pragma unroll
                    for (int dx = 0; dx < 3; ++dx)
                        F[i][dx] = *(const short8*)&s_h1[colbase + ((r0 + i)*36 + dx)*8];

                f32x4 acc0, acc1;
                #pragma unroll
                for (int i = 0; i < 4; ++i) { acc0[i] = 0.f; acc1[i] = 0.f; }
                #pragma unroll
                for (int i = 0; i < 3; ++i)
                    #pragma unroll
                    for (int dx = 0; dx < 3; ++dx)
                        acc0 = __builtin_amdgcn_mfma_f32_16x16x32_bf16(
                                 a2[i*3 + dx], F[i][dx], acc0, 0, 0, 0);
                #pragma unroll
                for (int i = 0; i < 3; ++i)
                    #pragma unroll
                    for (int dx = 0; dx < 3; ++dx)
                        acc1 = __builtin_amdgcn_mfma_f32_16x16x32_bf16(
                                 a2[i*3 + dx], F[i + 1][dx], acc1, 0, 0, 0);

                #pragma unroll
                for (int rr = 0; rr < 2; ++rr) {
                    f32x4 lg = rr ? acc1 : acc0;
                    int oy = r0 + rr, ox = ox0 + fl;
                    float num = 0.f, den = 0.f;
                    #pragma unroll
                    for (int q = 0; q < 4; ++q) {
                        int f = cg2*4 + q;           // conv2 output channel
                        if (f < 9) {
                            float e = __expf(lg[q]);
                            int fy = f/3, fx = f - fy*3;
                            float d = s_depth[t][(oy + fy)*34 + (ox + fx)];
                            den += e; num += e * d;
                        }
                    }
                    num += __shfl_xor(num, 16); den += __shfl_xor(den, 16);
                    num += __shfl_xor(num, 32); den += __shfl_xor(den, 32);
                    if (cg2 == 0)
                        out[(size_t)bz*HW + (size_t)(gy0 + oy)*WW + (gx0 + ox)] = num / den;
                }
            }
        }
    }
}

// ================= fallback: R6 fused kernel (ws too small) =================
#define FIMPLANEP (432*8 + 8)
#define FH1PLANEP (360*8 + 8)

__launch_bounds__(256, 4)
__global__ void fastprop_fused(const float* __restrict__ depth,
                               const float* __restrict__ img,
                               const short* __restrict__ ws_w1,
                               const short* __restrict__ ws_w2,
                               float* __restrict__ out)
{
    __shared__ short s_img[2*FIMPLANEP];
    __shared__ short s_h1 [4*FH1PLANEP];
    __shared__ float s_depth[340];

    const int tid = threadIdx.x;
    int nid = blockIdx.x;
    int oid = (nid & 7)*640 + (nid >> 3);
    int bz = oid / 1280; int rem = oid - bz*1280;
    int by = rem / 20;   int bx = rem - by*20;
    const int gy0 = by*8, gx0 = bx*32;

    const float* imgb = img   + (size_t)bz*16*HW;
    const float* dpb  = depth + (size_t)bz*HW;
    const int lane = tid & 63;
    const int wid  = tid >> 6;

    const int oc = lane & 31, cg = lane >> 5;
    short8 a1[10];
    #pragma unroll
    for (int t = 0; t < 10; ++t)
        a1[t] = *(const short8*)&ws_w1[t*512 + oc*16 + cg*8];
    short8 bb = (short8)0;
    bb[0] = (cg == 0) ? (short)0x3F80 : (short)0;

    for (int g = tid; g < 864; g += 256) {
        int pixel = g >> 1, half = g & 1;
        int iy = pixel / 36, ix = pixel - iy*36;
        int gy = gy0 + iy - 2, gx = gx0 + ix - 2;
        bool v = ((unsigned)gy < HH) && ((unsigned)gx < WW);
        int cy = min(max(gy, 0), HH-1), cx = min(max(gx, 0), WW-1);
        const float* p = imgb + (size_t)(half*8)*HW + cy*WW + cx;
        float m = v ? 1.f : 0.f;
        short8 vv;
        #pragma unroll
        for (int c = 0; c < 8; ++c) vv[c] = f2bf(m * p[c*HW]);
        *(short8*)&s_img[half*FIMPLANEP + pixel*8] = vv;
    }
    #pragma unroll
    for (int it = 0; it < 2; ++it) {
        int idx = tid + it*256;
        if (idx < 340) {
            int dty = idx / 34, dtx = idx - dty*34;
            int gy = min(max(gy0 + dty - 1, 0), HH-1);
            int gx = min(max(gx0 + dtx - 1, 0), WW-1);
            s_depth[idx] = dpb[gy*WW + gx];
        }
    }
    __syncthreads();

    {
        const int OFS1[9] = {0, 8, 16, 288, 296, 304, 576, 584, 592};
        const int px = lane & 31;
        #pragma unroll
        for (int gi = 0; gi < 3; ++gi) {
            int g    = wid + gi*4;
            int hp   = g*32 + px;
            int base = cg*FIMPLANEP + hp*8;
            f32x16 acc;
            #pragma unroll
            for (int i = 0; i < 16; ++i) acc[i] = 0.f;
            acc = __builtin_amdgcn_mfma_f32_32x32x16_bf16(a1[9], bb, acc, 0, 0, 0);
            #pragma unroll
            for (int t = 0; t < 9; ++t)
                acc = __builtin_amdgcn_mfma_f32_32x32x16_bf16(
                         a1[t], *(const short8*)&s_img[base + OFS1[t]], acc, 0, 0, 0);
            if (hp < 360) {
                unsigned hy = (unsigned)hp / 36u;
                int hx = hp - (int)hy*36;
                int gy = gy0 + (int)hy - 1, gx = gx0 + hx - 1;
                bool inb = ((unsigned)gy < HH) && ((unsigned)gx < WW);
                #pragma unroll
                for (int q = 0; q < 4; ++q) {
                    short4v h;
                    #pragma unroll
                    for (int j = 0; j < 4; ++j) {
                        float hv = fmaxf(acc[q*4 + j], 0.f);
                        h[j] = inb ? f2bf(hv) : (short)0;
                    }
                    *(short4v*)&s_h1[q*FH1PLANEP + hp*8 + 4*cg] = h;
                }
            }
        }
    }
    __syncthreads();

    {
        const int fl = lane & 15, cg2 = lane >> 4;
        short8 a2[9];
        #pragma unroll
        for (int t = 0; t < 9; ++t)
            a2[t] = *(const short8*)&ws_w2[t*512 + fl*32 + cg2*8];
        const int r0 = 2*wid;
        #pragma unroll
        for (int chh = 0; chh < 2; ++chh) {
            const int ox0 = chh*16;
            const int colbase = cg2*FH1PLANEP + (ox0 + fl)*8;
            short8 F[4][3];
            #pragma unroll
            for (int i = 0; i < 4; ++i)
                #pragma unroll
                for (int dx = 0; dx < 3; ++dx)
                    F[i][dx] = *(const short8*)&s_h1[colbase + ((r0 + i)*36 + dx)*8];
            f32x4 acc0, acc1;
            #pragma unroll
            for (int i = 0; i < 4; ++i) { acc0[i] = 0.f; acc1[i] = 0.f; }
            #pragma unroll
            for (int i = 0; i < 3; ++i)
                #pragma unroll
                for (int dx = 0; dx < 3; ++dx)
                    acc0 = __builtin_amdgcn_mfma_f32_16x16x32_bf16(a2[i*3+dx], F[i][dx], acc0, 0, 0, 0);
            #pragma unroll
            for (int i = 0; i < 3; ++i)
                #pragma unroll
                for (int dx = 0; dx < 3; ++dx)
                    acc1 = __builtin_amdgcn_mfma_f32_16x16x32_bf16(a2[i*3+dx], F[i+1][dx], acc1, 0, 0, 0);
            #pragma unroll
            for (int rr = 0; rr < 2; ++rr) {
                f32x4 lg = rr ? acc1 : acc0;
                int oy = r0 + rr, ox = ox0 + fl;
                float num = 0.f, den = 0.f;
                #pragma unroll
                for (int q = 0; q < 4; ++q) {
                    int f = cg2*4 + q;
                    if (f < 9) {
                        float e = __expf(lg[q]);
                        int fy = f/3, fx = f - fy*3;
                        float d = s_depth[(oy + fy)*34 + (ox + fx)];
                        den += e; num += e * d;
                    }
                }
                num += __shfl_xor(num, 16); den += __shfl_xor(den, 16);
                num += __shfl_xor(num, 32); den += __shfl_xor(den, 32);
                if (cg2 == 0)
                    out[(size_t)bz*HW + (size_t)(gy0 + oy)*WW + (gx0 + ox)] = num / den;
            }
        }
    }
}

extern "C" void kernel_launch(void* const* d_in, const int* in_sizes, int n_in,
                              void* d_out, int out_size, void* d_ws, size_t ws_size,
                              hipStream_t stream) {
    const float* depth = (const float*)d_in[0];
    const float* img   = (const float*)d_in[1];
    const float* w1    = (const float*)d_in[2];
    const float* b1    = (const float*)d_in[3];
    const float* gamma = (const float*)d_in[4];
    const float* beta  = (const float*)d_in[5];
    const float* rmean = (const float*)d_in[6];
    const float* rvar  = (const float*)d_in[7];
    const float* w2    = (const float*)d_in[8];
    float* out = (float*)d_out;

    short* ws_w1 = (short*)d_ws;                          // 5120 shorts
    short* ws_w2 = ws_w1 + 5120;                          // 4608 shorts

    const size_t OFF_IMG = 20480;
    const size_t SZ_IMG  = (size_t)NIP*32;                // 42,534,912 B
    const size_t OFF_DEP = OFF_IMG + SZ_IMG;
    const size_t SZ_DEP  = (size_t)NDP*4;                 //  5,279,808 B
    const size_t WS_NEEDED = OFF_DEP + SZ_DEP;            // ~47.8 MB

    prep_weights<<<16, 256, 0, stream>>>(w1, b1, gamma, beta, rmean, rvar, w2,
                                         ws_w1, ws_w2);

    if (ws_size >= WS_NEEDED) {
        short* img_pad   = (short*)((char*)d_ws + OFF_IMG);
        float* depth_pad = (float*)((char*)d_ws + OFF_DEP);
        prep_pad<<<(NIP + 255)/256, 256, 0, stream>>>(depth, img, img_pad, depth_pad);
        fastprop_main<<<2560, 256, 0, stream>>>(img_pad, depth_pad, ws_w1, ws_w2, out);
    } else {
        fastprop_fused<<<5120, 256, 0, stream>>>(depth, img, ws_w1, ws_w2, out);
    }
}